// Round 6
// baseline (252.069 us; speedup 1.0000x reference)
//
#include <hip/hip_runtime.h>
#include <hip/hip_bf16.h>

typedef unsigned int u32;
typedef unsigned short u16;
typedef short s8v __attribute__((ext_vector_type(8)));
typedef short s4v __attribute__((ext_vector_type(4)));
typedef float f4v __attribute__((ext_vector_type(4)));
typedef u32 u32x2 __attribute__((ext_vector_type(2)));

// Problem constants: B=2, L=4096, D=1024, HEADS=16, KEY=SPH=64, STEP=3
// new_len=4098, blocks P=1366, combos = B*3*H = 96
#define NBLK 1366
#define VROW 1376   // padded V row stride (16B aligned)
#define QSCALE 0.18033688011112042f   // 0.125 * log2(e), folded into Q

__device__ __forceinline__ u16 f2b(float f) {
  u32 u = __builtin_bit_cast(u32, f);
  u = (u + 0x7FFFu + ((u >> 16) & 1u)) >> 16;
  return (u16)u;
}

__device__ __forceinline__ u32 cvtpk(float a, float b) {
  u32 r;
  asm("v_cvt_pk_bf16_f32 %0, %1, %2" : "=v"(r) : "v"(a), "v"(b));
  return r;
}

__device__ __forceinline__ float fexp2(float x) {
#if defined(__has_builtin)
#if __has_builtin(__builtin_amdgcn_exp2f)
  return __builtin_amdgcn_exp2f(x);
#define FEXP2_DONE 1
#endif
#endif
#ifndef FEXP2_DONE
  float r;
  asm("v_exp_f32 %0, %1" : "=v"(r) : "v"(x));
  return r;
#endif
}

__device__ __forceinline__ void gll16(const void* g, void* l) {
  __builtin_amdgcn_global_load_lds(
      (const __attribute__((address_space(1))) u32*)g,
      (__attribute__((address_space(3))) u32*)l, 16, 0, 0);
}

__device__ __forceinline__ f4v mfma32(s8v a, s8v b, f4v c) {
  return __builtin_amdgcn_mfma_f32_16x16x32_bf16(a, b, c, 0, 0, 0);
}

__device__ __forceinline__ f4v mfma16(s4v a, s4v b, f4v c) {
#if defined(__has_builtin)
#if __has_builtin(__builtin_amdgcn_mfma_f32_16x16x16bf16_1k)
#define MFMA16_BUILTIN 1
#endif
#endif
#ifdef MFMA16_BUILTIN
  return __builtin_amdgcn_mfma_f32_16x16x16bf16_1k(a, b, c, 0, 0, 0);
#else
  f4v d;
  asm("v_mfma_f32_16x16x16_bf16 %0, %1, %2, %3" : "=v"(d) : "v"(a), "v"(b), "v"(c));
  return d;
#endif
}

// ---- pass 1: x (f32, [2][4096][1024]) -> xb (bf16, [8320][1024]); rows for
// padded t (4096,4097) and m>=8196 are zero.
__global__ __launch_bounds__(256) void k_convert_x(const float* __restrict__ x,
                                                   u16* __restrict__ xb) {
  int gid = blockIdx.x * 256 + threadIdx.x;
  long base = (long)gid * 8;
  if (base >= 8320L * 1024L) return;
  int m = (int)(base >> 10);
  int c = (int)(base & 1023);
  int b = m / 4098;
  int t = m - b * 4098;
  s8v pack;
  if (m < 8196 && t < 4096) {
    const float* src = x + ((size_t)b * 4096 + t) * 1024 + c;
    float4 v0 = *(const float4*)(src);
    float4 v1 = *(const float4*)(src + 4);
    pack[0] = (short)f2b(v0.x); pack[1] = (short)f2b(v0.y);
    pack[2] = (short)f2b(v0.z); pack[3] = (short)f2b(v0.w);
    pack[4] = (short)f2b(v1.x); pack[5] = (short)f2b(v1.y);
    pack[6] = (short)f2b(v1.z); pack[7] = (short)f2b(v1.w);
  } else {
#pragma unroll
    for (int i = 0; i < 8; ++i) pack[i] = 0;
  }
  *(s8v*)(xb + base) = pack;
}

// ---- pass 2: W [K=1024][N=1024] f32 -> Wt [N][K] bf16, for q,k,v (contiguous
// [3072][1024] so the GEMM sees one N=3072 B matrix)
__global__ __launch_bounds__(256) void k_transpose_w(const float* __restrict__ Wq,
                                                     const float* __restrict__ Wk,
                                                     const float* __restrict__ Wv,
                                                     u16* __restrict__ Wt) {
  const float* W = (blockIdx.z == 0) ? Wq : ((blockIdx.z == 1) ? Wk : Wv);
  u16* dst = Wt + (size_t)blockIdx.z * 1024 * 1024;
  __shared__ float tile[32][33];
  int n0 = blockIdx.x * 32, k0 = blockIdx.y * 32;
  int tx = threadIdx.x, ty = threadIdx.y;
#pragma unroll
  for (int i = 0; i < 4; ++i)
    tile[ty + i * 8][tx] = W[(size_t)(k0 + ty + i * 8) * 1024 + n0 + tx];
  __syncthreads();
#pragma unroll
  for (int i = 0; i < 4; ++i)
    dst[(size_t)(n0 + ty + i * 8) * 1024 + k0 + tx] = f2b(tile[tx][ty + i * 8]);
}

// ---- pass 3: fused qkv GEMM, M=8448(view) x N=3072 x K=1024.
// 256x256 tile, BK=32, 8 waves (2M x 4N; 128x64 per wave), 4-slot LDS ring
// (128 KiB), 2 phases per K-tile (16 MFMA each), 1 half-stage per phase,
// counted vmcnt(8) once per K-tile (3-tile prefetch lead; T3+T4), setprio
// around MFMA (T5). Ring safety: phase of tile t stages into slot (t+3)&3 =
// (t-1)&3, whose last readers (tile t-1) completed before tile t-1's trailing
// barrier (lgkm-complete via MFMA consumption). vmcnt(8)+barrier at tile t's
// last phase makes tile t+1's loads visible to all waves.
__global__ __launch_bounds__(512, 2) void k_gemm_qkv(const u16* __restrict__ xb,
                                                     const u16* __restrict__ Wt,
                                                     u16* __restrict__ Qp,
                                                     u16* __restrict__ Kp,
                                                     u16* __restrict__ Vt) {
  // bijective XCD swizzle (396 blocks = 8*49 + 4) per m204
  const int orig = blockIdx.x;
  const int xcd = orig & 7, sub = orig >> 3;
  const int wgid = (xcd < 4 ? xcd * 50 : 200 + (xcd - 4) * 49) + sub;
  const int nz = wgid / 33, mt = wgid - nz * 33;  // 12 n-tiles x 33 m-tiles
  const int m0 = mt * 256;
  const int n0g = nz * 256;
  const u16* Bg = Wt + (size_t)n0g * 1024;

  __shared__ __align__(16) u16 lds[4 * 16384];   // 4 ring slots x 32 KiB

  const int tid = threadIdx.x;
  const int lane = tid & 63;
  const int w = tid >> 6;                 // 8 waves
  const int wm = w >> 2, wn = w & 3;      // 2M x 4N
  const int lo = lane & 15, g = lane >> 4;

  // staging: thread covers row q*128 + (tid>>2), chunk slot tid&3 of a 64B
  // row; source chunk pre-swizzled (G21): csrc = slot ^ ((row%16)>>1 & 3).
  const int srow = tid >> 2;
  const int csrc = (tid & 3) ^ ((tid >> 3) & 3);
  // read-side swizzle byte offset (row%16 == lo on the read path)
  const int rsw = (g ^ ((lo >> 1) & 3)) << 4;

  const u16* gA = xb + (size_t)(m0 + srow) * 1024 + csrc * 8;
  const u16* gB = Bg + (size_t)srow * 1024 + csrc * 8;

  f4v acc[8][4];
#pragma unroll
  for (int i = 0; i < 8; ++i)
#pragma unroll
    for (int j = 0; j < 4; ++j) {
      f4v z = {0.f, 0.f, 0.f, 0.f};
      acc[i][j] = z;
    }
  s8v bf[4];

#define STAGE_H(T, Q)                                                        \
  {                                                                          \
    const int sT_ = (T), sQ_ = (Q);                                          \
    u16* d_ = lds + (sT_ & 3) * 16384 + sQ_ * 4096 + w * 512;                \
    gll16(gA + (size_t)sQ_ * 131072 + sT_ * 32, d_);                         \
    gll16(gB + (size_t)sQ_ * 131072 + sT_ * 32, d_ + 8192);                  \
  }

#define PHASE(T, Q, DOSTG, VMSTR, DOVM)                                      \
  {                                                                          \
    const int pT_ = (T);                                                     \
    const char* sA_ = (const char*)(lds + (pT_ & 3) * 16384);                \
    const char* sB_ = sA_ + 16384;                                           \
    s8v af_[4];                                                              \
    if (Q == 0) {                                                            \
      _Pragma("unroll")                                                      \
      for (int j = 0; j < 4; ++j)                                            \
        bf[j] = *(const s8v*)(sB_ + (wn * 64 + j * 16 + lo) * 64 + rsw);     \
    }                                                                        \
    _Pragma("unroll")                                                        \
    for (int i = 0; i < 4; ++i)                                              \
      af_[i] = *(const s8v*)(sA_ + (wm * 128 + Q * 64 + i * 16 + lo) * 64 + rsw); \
    if (DOSTG) { STAGE_H(pT_ + 3, Q); }                                      \
    if (DOVM) { asm volatile("s_waitcnt vmcnt(" VMSTR ")" ::: "memory"); }   \
    __builtin_amdgcn_s_barrier();                                            \
    asm volatile("s_waitcnt lgkmcnt(0)" ::: "memory");                       \
    __builtin_amdgcn_sched_barrier(0);                                       \
    __builtin_amdgcn_s_setprio(1);                                           \
    _Pragma("unroll")                                                        \
    for (int i = 0; i < 4; ++i)                                              \
      _Pragma("unroll")                                                      \
      for (int j = 0; j < 4; ++j)                                            \
        acc[Q * 4 + i][j] = mfma32(af_[i], bf[j], acc[Q * 4 + i][j]);        \
    __builtin_amdgcn_s_setprio(0);                                           \
    __builtin_amdgcn_s_barrier();                                            \
  }

  // prologue: stage K-tiles 0,1,2 (12 loads/wave in flight), wait tile 0
  STAGE_H(0, 0); STAGE_H(0, 1);
  STAGE_H(1, 0); STAGE_H(1, 1);
  STAGE_H(2, 0); STAGE_H(2, 1);
  asm volatile("s_waitcnt vmcnt(8)" ::: "memory");
  __builtin_amdgcn_s_barrier();

#pragma unroll 1
  for (int t = 0; t < 29; ++t) {
    PHASE(t, 0, true, "0", false);
    PHASE(t, 1, true, "8", true);
  }
  PHASE(29, 0, false, "0", false);
  PHASE(29, 1, false, "4", true);
  PHASE(30, 0, false, "0", false);
  PHASE(30, 1, false, "0", true);
  PHASE(31, 0, false, "0", false);
  PHASE(31, 1, false, "0", false);

#undef PHASE
#undef STAGE_H

  // epilogue: m -> (b, t) -> (s, p); n -> (zid, h, d); combo = (b*3+s)*16+h
  const int zid = n0g >> 10;
  if (zid != 2) {
    const float esc = (zid == 0) ? QSCALE : 1.0f;
    u16* dq = (zid == 0) ? Qp : Kp;
#pragma unroll
    for (int ii = 0; ii < 8; ++ii) {
#pragma unroll
      for (int r = 0; r < 4; ++r) {
        int m = m0 + wm * 128 + ii * 16 + g * 4 + r;
        if (m >= 8196) continue;
        int b = m / 4098;
        int t = m - b * 4098;
        int s = t % 3;
        int p = t / 3;
        int cb = (b * 3 + s) * 16;
#pragma unroll
        for (int j = 0; j < 4; ++j) {
          int n = n0g + wn * 64 + j * 16 + lo;
          int h = (n >> 6) & 15, d = n & 63;
          dq[(size_t)((cb + h) * NBLK + p) * 64 + d] = f2b(acc[ii][j][r] * esc);
        }
      }
    }
  } else {
    // V: stage 256x256 result into LDS (reuses the 128 KiB ring; safe after
    // the final trailing barrier), then write per-(n,s) sequential p-runs so
    // L2 lines complete back-to-back (keeps WRITE_SIZE at the ideal).
    u16* tile = lds;
#pragma unroll
    for (int ii = 0; ii < 8; ++ii)
#pragma unroll
      for (int r = 0; r < 4; ++r) {
        int ml = wm * 128 + ii * 16 + g * 4 + r;
#pragma unroll
        for (int j = 0; j < 4; ++j) {
          int nl = wn * 64 + j * 16 + lo;
          tile[ml * 256 + nl] = f2b(acc[ii][j][r]);
        }
      }
    __syncthreads();
    for (int st = tid; st < 768; st += 512) {
      int nl = st & 255;
      int s = st >> 8;                 // 0..2
      int n = n0g + nl;
      int h = (n >> 6) & 15, d = n & 63;
      for (int b = 0; b < 2; ++b) {
        int mlo = m0 > b * 4098 ? m0 : b * 4098;
        int cap = b * 4098 + 4096;     // t < 4096
        int mhi = (m0 + 256 < cap) ? m0 + 256 : cap;
        if (mlo >= mhi) continue;
        int t_lo = mlo - b * 4098;
        int add = (s - (t_lo % 3) + 3) % 3;
        int t = t_lo + add;
        int tend = mhi - b * 4098;
        u16* dst = Vt + (size_t)(((b * 3 + s) * 16 + h) * 64 + d) * VROW;
        for (; t < tend; t += 3)
          dst[t / 3] = tile[(b * 4098 + t - m0) * 256 + nl];
      }
    }
  }
}

// ---- pass 4: per-(b,h,s) attention over 1366 blocks, single-pass softmax
// (no max subtraction; logits tiny), local logits handled by E-doubling +
// den fixup. den via MFMA with ones-fragment. XCD swizzle: 12 combos/XCD.
__global__ __launch_bounds__(256) void k_attn(const u16* __restrict__ Qp,
                                              const u16* __restrict__ Kp,
                                              const u16* __restrict__ Vt,
                                              float* __restrict__ out) {
  const int wg = blockIdx.x;                 // 2112 blocks, 2112%8==0
  const int idx = (wg & 7) * 264 + (wg >> 3);
  const int combo = idx / 22;
  const int q0 = (idx % 22) * 64;
  const int b = combo / 48;
  const int rem = combo - b * 48;
  const int s = rem >> 4;
  const int h = rem & 15;
  const int tid = threadIdx.x, lane = tid & 63, w = tid >> 6;
  const int lo = lane & 15, g = lane >> 4;

  const u16* Qg = Qp + (size_t)combo * (NBLK * 64);
  const u16* Kg = Kp + (size_t)combo * (NBLK * 64);
  const u16* Vg = Vt + (size_t)combo * (64 * VROW);

  __shared__ __align__(16) u16 Kl[64 * 64];
  __shared__ __align__(16) u16 Vl[64 * 64];

  const int pq_e = q0 + w * 16 + lo;       // query owned by this lane (E rows)
  const int qc = (pq_e < NBLK) ? pq_e : (NBLK - 1);
  s8v qf0 = *(const s8v*)(Qg + (size_t)qc * 64 + g * 8);
  s8v qf1 = *(const s8v*)(Qg + (size_t)qc * 64 + 32 + g * 8);

  s4v onesf;
  onesf[0] = onesf[1] = onesf[2] = onesf[3] = (short)0x3F80;  // bf16 1.0

  f4v oacc[4];
#pragma unroll
  for (int i = 0; i < 4; ++i) {
    f4v z = {0.f, 0.f, 0.f, 0.f};
    oacc[i] = z;
  }
  f4v den_acc = {0.f, 0.f, 0.f, 0.f};

  const int lrow = lane >> 3;
  const int schunk = (lane & 7) ^ lrow;

  for (int j0 = 0; j0 < NBLK; j0 += 64) {
    __syncthreads();
#pragma unroll
    for (int c = 0; c < 2; ++c) {
      int rloc = w * 16 + c * 8 + lrow;
      gll16(Kg + (size_t)(j0 + rloc) * 64 + schunk * 8, Kl + (w * 16 + c * 8) * 64);
      gll16(Vg + (size_t)rloc * VROW + j0 + schunk * 8, Vl + (w * 16 + c * 8) * 64);
    }
    __syncthreads();

    // S^T = K * Q^T : sacc[kb] holds S[j = j0+kb*16+g*4+r][q = q0+w*16+lo],
    // already scaled by 0.125*log2e (folded into Q).
    f4v sacc[4];
    __builtin_amdgcn_s_setprio(1);
#pragma unroll
    for (int kb = 0; kb < 4; ++kb) {
      f4v z = {0.f, 0.f, 0.f, 0.f};
      int row = kb * 16 + lo;
      int sw = (row & 7) << 4;
      s8v kf0 = *(const s8v*)((const char*)Kl + row * 128 + ((g * 16) ^ sw));
      s8v kf1 = *(const s8v*)((const char*)Kl + row * 128 + ((64 + g * 16) ^ sw));
      z = mfma32(kf0, qf0, z);
      sacc[kb] = mfma32(kf1, qf1, z);
    }
    __builtin_amdgcn_s_setprio(0);

    // E = exp2(S'); near/edge tiles double where |j-p|<=2 and zero j>=NBLK.
    s4v ef[4];
    const bool special = (j0 >= q0 - 64 && j0 <= q0 + 64) || (j0 + 64 > NBLK);
    if (special) {
#pragma unroll
      for (int kb = 0; kb < 4; ++kb) {
        float e[4];
#pragma unroll
        for (int r = 0; r < 4; ++r) {
          int j = j0 + kb * 16 + g * 4 + r;
          float ev = fexp2(sacc[kb][r]);
          int dd = j - pq_e;
          float fac = (j < NBLK) ? (((dd <= 2) && (dd >= -2)) ? 2.f : 1.f) : 0.f;
          e[r] = ev * fac;
        }
        u32x2 w2;
        w2[0] = cvtpk(e[0], e[1]);
        w2[1] = cvtpk(e[2], e[3]);
        ef[kb] = __builtin_bit_cast(s4v, w2);
      }
    } else {
#pragma unroll
      for (int kb = 0; kb < 4; ++kb) {
        u32x2 w2;
        w2[0] = cvtpk(fexp2(sacc[kb][0]), fexp2(sacc[kb][1]));
        w2[1] = cvtpk(fexp2(sacc[kb][2]), fexp2(sacc[kb][3]));
        ef[kb] = __builtin_bit_cast(s4v, w2);
      }
    }

    // O += E * V ; den += E * ones (all on the MFMA pipe)
    __builtin_amdgcn_s_setprio(1);
#pragma unroll
    for (int kb = 0; kb < 4; ++kb)
      den_acc = mfma16(ef[kb], onesf, den_acc);
#pragma unroll
    for (int db = 0; db < 4; ++db) {
      int row = db * 16 + lo;
      int sw = (row & 7) << 4;
#pragma unroll
      for (int kb = 0; kb < 4; ++kb) {
        s4v vf = *(const s4v*)((const char*)Vl + row * 128 + ((kb * 32 + g * 8) ^ sw));
        oacc[db] = mfma16(ef[kb], vf, oacc[db]);
      }
    }
    __builtin_amdgcn_s_setprio(0);
  }

  // den_acc[r] = den for q = q0 + w*16 + g*4 + r (identical across lo lanes).
  // Out-of-range local patches contribute exp(0)=1 each.
  const int hbase = h * 64;
#pragma unroll
  for (int r = 0; r < 4; ++r) {
    int pq = q0 + w * 16 + g * 4 + r;
    float dden = den_acc[r];
    dden += (pq == 0 || pq == NBLK - 1) ? 2.f : ((pq == 1 || pq == NBLK - 2) ? 1.f : 0.f);
    float rr = 1.f / dden;
    int t = 3 * pq + s;
    if (pq < NBLK && t < 4096) {
      float* orow = out + ((size_t)b * 4096 + t) * 1024 + hbase;
#pragma unroll
      for (int db = 0; db < 4; ++db)
        orow[db * 16 + lo] = oacc[db][r] * rr;
    }
  }
}

extern "C" void kernel_launch(void* const* d_in, const int* in_sizes, int n_in,
                              void* d_out, int out_size, void* d_ws, size_t ws_size,
                              hipStream_t stream) {
  const float* x  = (const float*)d_in[0];
  const float* Wq = (const float*)d_in[1];
  const float* Wk = (const float*)d_in[2];
  const float* Wv = (const float*)d_in[3];
  float* out = (float*)d_out;

  u16* ws = (u16*)d_ws;
  u16* xb = ws;                        // 8320*1024            = 8,519,680 elems
  u16* Wt = xb + 8519680;              // 3*1024*1024          = 3,145,728
  u16* Qp = Wt + 3145728;              // 96*1366*64           = 8,392,704
  u16* Kp = Qp + 8392704;              // 8,392,704
  u16* Vt = Kp + 8392704;              // 96*64*1376           = 8,454,144 (+256 guard)
  // GEMM m-tail (rows 8320..8447) over-reads into Wt region; those rows'
  // outputs are skipped in the epilogue (m>=8196), so garbage is harmless.

  k_convert_x<<<4160, 256, 0, stream>>>(x, xb);
  k_transpose_w<<<dim3(32, 32, 3), dim3(32, 8), 0, stream>>>(Wq, Wk, Wv, Wt);
  // zero V (covers pad columns p in [1366,1376)) + guard region after it, so
  // masked over-reads in the attention staging are always finite.
  hipMemsetAsync(Vt, 0, (size_t)(8454144 + 256) * sizeof(u16), stream);
  k_gemm_qkv<<<dim3(396), 512, 0, stream>>>(xb, Wt, Qp, Kp, Vt);
  k_attn<<<dim3(2112), 256, 0, stream>>>(Qp, Kp, Vt, out);
}

// Round 7
// 218.733 us; speedup vs baseline: 1.1524x; 1.1524x over previous
//
#include <hip/hip_runtime.h>
#include <hip/hip_bf16.h>

typedef unsigned int u32;
typedef unsigned short u16;
typedef short s8v __attribute__((ext_vector_type(8)));
typedef short s4v __attribute__((ext_vector_type(4)));
typedef float f4v __attribute__((ext_vector_type(4)));
typedef u32 u32x2 __attribute__((ext_vector_type(2)));

// Problem constants: B=2, L=4096, D=1024, HEADS=16, KEY=SPH=64, STEP=3
// new_len=4098, blocks P=1366, combos = B*3*H = 96
#define NBLK 1366
#define VROW 1376   // padded V row stride (16B aligned)
#define QSCALE 0.18033688011112042f   // 0.125 * log2(e), folded into Q

__device__ __forceinline__ u16 f2b(float f) {
  u32 u = __builtin_bit_cast(u32, f);
  u = (u + 0x7FFFu + ((u >> 16) & 1u)) >> 16;
  return (u16)u;
}

__device__ __forceinline__ u32 cvtpk(float a, float b) {
  u32 r;
  asm("v_cvt_pk_bf16_f32 %0, %1, %2" : "=v"(r) : "v"(a), "v"(b));
  return r;
}

__device__ __forceinline__ float fexp2(float x) {
#if defined(__has_builtin)
#if __has_builtin(__builtin_amdgcn_exp2f)
  return __builtin_amdgcn_exp2f(x);
#define FEXP2_DONE 1
#endif
#endif
#ifndef FEXP2_DONE
  float r;
  asm("v_exp_f32 %0, %1" : "=v"(r) : "v"(x));
  return r;
#endif
}

__device__ __forceinline__ void gll16(const void* g, void* l) {
  __builtin_amdgcn_global_load_lds(
      (const __attribute__((address_space(1))) u32*)g,
      (__attribute__((address_space(3))) u32*)l, 16, 0, 0);
}

__device__ __forceinline__ f4v mfma32(s8v a, s8v b, f4v c) {
  return __builtin_amdgcn_mfma_f32_16x16x32_bf16(a, b, c, 0, 0, 0);
}

__device__ __forceinline__ f4v mfma16(s4v a, s4v b, f4v c) {
#if defined(__has_builtin)
#if __has_builtin(__builtin_amdgcn_mfma_f32_16x16x16bf16_1k)
#define MFMA16_BUILTIN 1
#endif
#endif
#ifdef MFMA16_BUILTIN
  return __builtin_amdgcn_mfma_f32_16x16x16bf16_1k(a, b, c, 0, 0, 0);
#else
  f4v d;
  asm("v_mfma_f32_16x16x16_bf16 %0, %1, %2, %3" : "=v"(d) : "v"(a), "v"(b), "v"(c));
  return d;
#endif
}

// ---- pass 1: x (f32, [2][4096][1024]) -> xb (bf16, [8320][1024]); rows for
// padded t (4096,4097) and m>=8196 are zero.
__global__ __launch_bounds__(256) void k_convert_x(const float* __restrict__ x,
                                                   u16* __restrict__ xb) {
  int gid = blockIdx.x * 256 + threadIdx.x;
  long base = (long)gid * 8;
  if (base >= 8320L * 1024L) return;
  int m = (int)(base >> 10);
  int c = (int)(base & 1023);
  int b = m / 4098;
  int t = m - b * 4098;
  s8v pack;
  if (m < 8196 && t < 4096) {
    const float* src = x + ((size_t)b * 4096 + t) * 1024 + c;
    float4 v0 = *(const float4*)(src);
    float4 v1 = *(const float4*)(src + 4);
    pack[0] = (short)f2b(v0.x); pack[1] = (short)f2b(v0.y);
    pack[2] = (short)f2b(v0.z); pack[3] = (short)f2b(v0.w);
    pack[4] = (short)f2b(v1.x); pack[5] = (short)f2b(v1.y);
    pack[6] = (short)f2b(v1.z); pack[7] = (short)f2b(v1.w);
  } else {
#pragma unroll
    for (int i = 0; i < 8; ++i) pack[i] = 0;
  }
  *(s8v*)(xb + base) = pack;
}

// ---- pass 2: W [K=1024][N=1024] f32 -> Wt [N][K] bf16, for q,k,v
__global__ __launch_bounds__(256) void k_transpose_w(const float* __restrict__ Wq,
                                                     const float* __restrict__ Wk,
                                                     const float* __restrict__ Wv,
                                                     u16* __restrict__ Wt) {
  const float* W = (blockIdx.z == 0) ? Wq : ((blockIdx.z == 1) ? Wk : Wv);
  u16* dst = Wt + (size_t)blockIdx.z * 1024 * 1024;
  __shared__ float tile[32][33];
  int n0 = blockIdx.x * 32, k0 = blockIdx.y * 32;
  int tx = threadIdx.x, ty = threadIdx.y;
#pragma unroll
  for (int i = 0; i < 4; ++i)
    tile[ty + i * 8][tx] = W[(size_t)(k0 + ty + i * 8) * 1024 + n0 + tx];
  __syncthreads();
#pragma unroll
  for (int i = 0; i < 4; ++i)
    dst[(size_t)(n0 + ty + i * 8) * 1024 + k0 + tx] = f2b(tile[tx][ty + i * 8]);
}

// ---- pass 3: qkv GEMM, 128x128 tile, BK=32, 2-slot LDS ring with COUNTED
// vmcnt (T4 on the multi-block 128^2 base): stage(t+1) stays in flight across
// the whole iteration computing tile t; vmcnt never drains to 0 until the
// final tile. 32 KB LDS -> ~5 blocks/CU of TLP on top.
// Data-ready: per-wave vmcnt(4) leaves only stage(t+1)'s 4 loads outstanding
// (stage(t) complete), then s_barrier joins all waves -> slot t&1 valid.
// Slot-reuse: readers of slot s in iter t finish via lgkmcnt(0) before iter
// t's trailing barrier; the overwriting stage (iter t+1) issues after it.
// Epilogue: Q/K direct coalesced stores; V transposed through LDS with
// per-thread sequential p-runs so L2 lines complete back-to-back.
__global__ __launch_bounds__(256) void k_gemm_qkv(const u16* __restrict__ xb,
                                                  const u16* __restrict__ Wt,
                                                  u16* __restrict__ Qp,
                                                  u16* __restrict__ Kp,
                                                  u16* __restrict__ Vt) {
  const int zid = blockIdx.z;
  const int m0 = blockIdx.x * 128;
  const int n0 = blockIdx.y * 128;
  const u16* Bg = Wt + (size_t)zid * 1024 * 1024 + (size_t)n0 * 1024;

  // 32 KB: two A buffers (128x32) + two B buffers; reused post-loop as the
  // 128x128 V-transpose tile.
  __shared__ __align__(16) u16 shl[16384];
  u16* A0 = shl;
  u16* A1 = shl + 4096;
  u16* B0 = shl + 8192;
  u16* B1 = shl + 12288;

  const int tid = threadIdx.x;
  const int lane = tid & 63;
  const int w = tid >> 6;
  const int wr = w >> 1, wc = w & 1;
  const int lo = lane & 15, g = lane >> 4;

  // staging geometry (validated): rows are 64B (32 u16, 4 chunks of 16B);
  // stored chunk slot = lane&3, source chunk = slot ^ swz(row), swz(r) =
  // (r>>1)&3; read back global chunk g at slot g ^ swz(row).
  const int lrow = lane >> 2;
  const int csrc = (lane & 3) ^ ((lane >> 3) & 3);
  const int rsw = (g ^ ((lo >> 1) & 3)) << 4;

  f4v acc[4][4];
#pragma unroll
  for (int i = 0; i < 4; ++i)
#pragma unroll
    for (int j = 0; j < 4; ++j) {
      f4v z = {0.f, 0.f, 0.f, 0.f};
      acc[i][j] = z;
    }

  auto stage = [&](int kt, u16* Ab, u16* Bb) {
#pragma unroll
    for (int c = 0; c < 2; ++c) {
      int rloc = w * 32 + c * 16 + lrow;
      gll16(xb + (size_t)(m0 + rloc) * 1024 + kt + csrc * 8,
            Ab + (w * 32 + c * 16) * 32);
      gll16(Bg + (size_t)rloc * 1024 + kt + csrc * 8,
            Bb + (w * 32 + c * 16) * 32);
    }
  };

  auto compute = [&](const u16* Ab, const u16* Bb) {
    s8v af[4], bf[4];
#pragma unroll
    for (int i = 0; i < 4; ++i) {
      int ar = wr * 64 + i * 16 + lo;
      af[i] = *(const s8v*)((const char*)Ab + ar * 64 + rsw);
      int br = wc * 64 + i * 16 + lo;
      bf[i] = *(const s8v*)((const char*)Bb + br * 64 + rsw);
    }
    __builtin_amdgcn_s_setprio(1);
#pragma unroll
    for (int i = 0; i < 4; ++i)
#pragma unroll
      for (int j = 0; j < 4; ++j)
        acc[i][j] = mfma32(af[i], bf[j], acc[i][j]);
    __builtin_amdgcn_s_setprio(0);
  };

#define BAR_VM4                                             \
  asm volatile("s_waitcnt vmcnt(4)" ::: "memory");          \
  __builtin_amdgcn_s_barrier();                             \
  asm volatile("" ::: "memory");
#define BAR_LGKM                                            \
  asm volatile("s_waitcnt lgkmcnt(0)" ::: "memory");        \
  __builtin_amdgcn_s_barrier();                             \
  asm volatile("" ::: "memory");

  // tiles 0..31 (kt = tile*32); slots alternate A0/B0 (even), A1/B1 (odd)
  stage(0, A0, B0);
#pragma unroll 1
  for (int kk = 0; kk < 15; ++kk) {
    int kt = kk * 64;
    stage(kt + 32, A1, B1);        // tile 2kk+1
    BAR_VM4                        // tile 2kk ready everywhere
    compute(A0, B0);
    BAR_LGKM                       // slot 0 readers done
    stage(kt + 64, A0, B0);        // tile 2kk+2
    BAR_VM4                        // tile 2kk+1 ready
    compute(A1, B1);
    BAR_LGKM                       // slot 1 readers done
  }
  // tile 30 (staged in kk=14), stage tile 31
  stage(31 * 32, A1, B1);
  BAR_VM4
  compute(A0, B0);
  BAR_LGKM
  // tile 31: last -- drain fully
  asm volatile("s_waitcnt vmcnt(0)" ::: "memory");
  __builtin_amdgcn_s_barrier();
  asm volatile("" ::: "memory");
  compute(A1, B1);
  __syncthreads();   // protects LDS reuse by the V epilogue

#undef BAR_VM4
#undef BAR_LGKM

  // epilogue: m -> (b, t) -> (s, p); n -> (h, d); combo = (b*3+s)*16+h
  const float esc = (zid == 0) ? QSCALE : 1.0f;
  if (zid != 2) {
    u16* dq = (zid == 0) ? Qp : Kp;
#pragma unroll
    for (int i = 0; i < 4; ++i) {
#pragma unroll
      for (int r = 0; r < 4; ++r) {
        int m = m0 + wr * 64 + i * 16 + g * 4 + r;
        if (m >= 8196) continue;
        int b = m / 4098;
        int t = m - b * 4098;
        int s = t % 3;
        int p = t / 3;
        int cb = (b * 3 + s) * 16;
#pragma unroll
        for (int j = 0; j < 4; ++j) {
          int n = n0 + wc * 64 + j * 16 + lo;
          int h = n >> 6, d = n & 63;
          dq[(size_t)((cb + h) * NBLK + p) * 64 + d] = f2b(acc[i][j][r] * esc);
        }
      }
    }
  } else {
    // V: stage results into LDS tile [m_local][n_local] (32 KB, aliases the
    // staging buffers -- safe after the __syncthreads above), then each
    // thread writes one (n,s) stream of consecutive p as sequential u16
    // stores (L2 lines complete back-to-back -> no write amplification).
    u16* tile = shl;
#pragma unroll
    for (int i = 0; i < 4; ++i)
#pragma unroll
      for (int r = 0; r < 4; ++r) {
        int ml = wr * 64 + i * 16 + g * 4 + r;
#pragma unroll
        for (int j = 0; j < 4; ++j) {
          int nl = wc * 64 + j * 16 + lo;
          tile[ml * 128 + nl] = f2b(acc[i][j][r]);
        }
      }
    __syncthreads();
    for (int pair = tid; pair < 384; pair += 256) {
      int nl = pair & 127;
      int s = pair >> 7;               // 0,1 then 2
      int n = n0 + nl;
      int h = n >> 6, d = n & 63;
      for (int b = 0; b < 2; ++b) {
        int mlo = m0 > b * 4098 ? m0 : b * 4098;
        int cap = b * 4098 + 4096;     // t < 4096
        int mhi = (m0 + 128 < cap) ? m0 + 128 : cap;
        if (mlo >= mhi) continue;
        int t_lo = mlo - b * 4098;
        int add = (s - (t_lo % 3) + 3) % 3;
        int t = t_lo + add;
        int tend = mhi - b * 4098;
        u16* dst = Vt + (size_t)(((b * 3 + s) * 16 + h) * 64 + d) * VROW;
        for (; t < tend; t += 3)
          dst[t / 3] = tile[(b * 4098 + t - m0) * 128 + nl];
      }
    }
  }
}

// ---- pass 4: per-(b,h,s) attention over 1366 blocks, single-pass softmax
// (no max subtraction; logits tiny), local logits handled by E-doubling +
// den fixup. den via MFMA with ones-fragment. XCD swizzle: 12 combos/XCD.
__global__ __launch_bounds__(256) void k_attn(const u16* __restrict__ Qp,
                                              const u16* __restrict__ Kp,
                                              const u16* __restrict__ Vt,
                                              float* __restrict__ out) {
  const int wg = blockIdx.x;                 // 2112 blocks, 2112%8==0
  const int idx = (wg & 7) * 264 + (wg >> 3);
  const int combo = idx / 22;
  const int q0 = (idx % 22) * 64;
  const int b = combo / 48;
  const int rem = combo - b * 48;
  const int s = rem >> 4;
  const int h = rem & 15;
  const int tid = threadIdx.x, lane = tid & 63, w = tid >> 6;
  const int lo = lane & 15, g = lane >> 4;

  const u16* Qg = Qp + (size_t)combo * (NBLK * 64);
  const u16* Kg = Kp + (size_t)combo * (NBLK * 64);
  const u16* Vg = Vt + (size_t)combo * (64 * VROW);

  __shared__ __align__(16) u16 Kl[64 * 64];
  __shared__ __align__(16) u16 Vl[64 * 64];

  const int pq_e = q0 + w * 16 + lo;       // query owned by this lane (E rows)
  const int qc = (pq_e < NBLK) ? pq_e : (NBLK - 1);
  s8v qf0 = *(const s8v*)(Qg + (size_t)qc * 64 + g * 8);
  s8v qf1 = *(const s8v*)(Qg + (size_t)qc * 64 + 32 + g * 8);

  s4v onesf;
  onesf[0] = onesf[1] = onesf[2] = onesf[3] = (short)0x3F80;  // bf16 1.0

  f4v oacc[4];
#pragma unroll
  for (int i = 0; i < 4; ++i) {
    f4v z = {0.f, 0.f, 0.f, 0.f};
    oacc[i] = z;
  }
  f4v den_acc = {0.f, 0.f, 0.f, 0.f};

  const int lrow = lane >> 3;
  const int schunk = (lane & 7) ^ lrow;

  for (int j0 = 0; j0 < NBLK; j0 += 64) {
    __syncthreads();
#pragma unroll
    for (int c = 0; c < 2; ++c) {
      int rloc = w * 16 + c * 8 + lrow;
      gll16(Kg + (size_t)(j0 + rloc) * 64 + schunk * 8, Kl + (w * 16 + c * 8) * 64);
      gll16(Vg + (size_t)rloc * VROW + j0 + schunk * 8, Vl + (w * 16 + c * 8) * 64);
    }
    __syncthreads();

    // S^T = K * Q^T : sacc[kb] holds S[j = j0+kb*16+g*4+r][q = q0+w*16+lo],
    // already scaled by 0.125*log2e (folded into Q).
    f4v sacc[4];
    __builtin_amdgcn_s_setprio(1);
#pragma unroll
    for (int kb = 0; kb < 4; ++kb) {
      f4v z = {0.f, 0.f, 0.f, 0.f};
      int row = kb * 16 + lo;
      int sw = (row & 7) << 4;
      s8v kf0 = *(const s8v*)((const char*)Kl + row * 128 + ((g * 16) ^ sw));
      s8v kf1 = *(const s8v*)((const char*)Kl + row * 128 + ((64 + g * 16) ^ sw));
      z = mfma32(kf0, qf0, z);
      sacc[kb] = mfma32(kf1, qf1, z);
    }
    __builtin_amdgcn_s_setprio(0);

    // E = exp2(S'); near/edge tiles double where |j-p|<=2 and zero j>=NBLK.
    s4v ef[4];
    const bool special = (j0 >= q0 - 64 && j0 <= q0 + 64) || (j0 + 64 > NBLK);
    if (special) {
#pragma unroll
      for (int kb = 0; kb < 4; ++kb) {
        float e[4];
#pragma unroll
        for (int r = 0; r < 4; ++r) {
          int j = j0 + kb * 16 + g * 4 + r;
          float ev = fexp2(sacc[kb][r]);
          int dd = j - pq_e;
          float fac = (j < NBLK) ? (((dd <= 2) && (dd >= -2)) ? 2.f : 1.f) : 0.f;
          e[r] = ev * fac;
        }
        u32x2 w2;
        w2[0] = cvtpk(e[0], e[1]);
        w2[1] = cvtpk(e[2], e[3]);
        ef[kb] = __builtin_bit_cast(s4v, w2);
      }
    } else {
#pragma unroll
      for (int kb = 0; kb < 4; ++kb) {
        u32x2 w2;
        w2[0] = cvtpk(fexp2(sacc[kb][0]), fexp2(sacc[kb][1]));
        w2[1] = cvtpk(fexp2(sacc[kb][2]), fexp2(sacc[kb][3]));
        ef[kb] = __builtin_bit_cast(s4v, w2);
      }
    }

    // O += E * V ; den += E * ones (all on the MFMA pipe)
    __builtin_amdgcn_s_setprio(1);
#pragma unroll
    for (int kb = 0; kb < 4; ++kb)
      den_acc = mfma16(ef[kb], onesf, den_acc);
#pragma unroll
    for (int db = 0; db < 4; ++db) {
      int row = db * 16 + lo;
      int sw = (row & 7) << 4;
#pragma unroll
      for (int kb = 0; kb < 4; ++kb) {
        s4v vf = *(const s4v*)((const char*)Vl + row * 128 + ((kb * 32 + g * 8) ^ sw));
        oacc[db] = mfma16(ef[kb], vf, oacc[db]);
      }
    }
    __builtin_amdgcn_s_setprio(0);
  }

  // den_acc[r] = den for q = q0 + w*16 + g*4 + r (identical across lo lanes).
  // Out-of-range local patches contribute exp(0)=1 each.
  const int hbase = h * 64;
#pragma unroll
  for (int r = 0; r < 4; ++r) {
    int pq = q0 + w * 16 + g * 4 + r;
    float dden = den_acc[r];
    dden += (pq == 0 || pq == NBLK - 1) ? 2.f : ((pq == 1 || pq == NBLK - 2) ? 1.f : 0.f);
    float rr = 1.f / dden;
    int t = 3 * pq + s;
    if (pq < NBLK && t < 4096) {
      float* orow = out + ((size_t)b * 4096 + t) * 1024 + hbase;
#pragma unroll
      for (int db = 0; db < 4; ++db)
        orow[db * 16 + lo] = oacc[db][r] * rr;
    }
  }
}

extern "C" void kernel_launch(void* const* d_in, const int* in_sizes, int n_in,
                              void* d_out, int out_size, void* d_ws, size_t ws_size,
                              hipStream_t stream) {
  const float* x  = (const float*)d_in[0];
  const float* Wq = (const float*)d_in[1];
  const float* Wk = (const float*)d_in[2];
  const float* Wv = (const float*)d_in[3];
  float* out = (float*)d_out;

  u16* ws = (u16*)d_ws;
  u16* xb = ws;                        // 8320*1024            = 8,519,680 elems
  u16* Wt = xb + 8519680;              // 3*1024*1024          = 3,145,728
  u16* Qp = Wt + 3145728;              // 96*1366*64           = 8,392,704
  u16* Kp = Qp + 8392704;              // 8,392,704
  u16* Vt = Kp + 8392704;              // 96*64*1376           = 8,454,144 (+256 guard)

  k_convert_x<<<4160, 256, 0, stream>>>(x, xb);
  k_transpose_w<<<dim3(32, 32, 3), dim3(32, 8), 0, stream>>>(Wq, Wk, Wv, Wt);
  // zero V (covers pad columns p in [1366,1376)) + guard region after it, so
  // masked over-reads in the attention staging are always finite.
  hipMemsetAsync(Vt, 0, (size_t)(8454144 + 256) * sizeof(u16), stream);
  k_gemm_qkv<<<dim3(65, 8, 3), 256, 0, stream>>>(xb, Wt, Qp, Kp, Vt);
  k_attn<<<dim3(2112), 256, 0, stream>>>(Qp, Kp, Vt, out);
}